// Round 1
// baseline (26.850 us; speedup 1.0000x reference)
//
#include <hip/hip_runtime.h>

// Problem constants (from reference): D=16384, P=126, S=128, E=4096, NODES=256.
// out[n][d] = sum_k W[n][k] * F[k][d], n in [0,128), F = [loss; prev_loss; params].
#define DCOLS 16384
#define COLS_PER_BLOCK 1024   // 256 threads * float4
#define CHUNKS (DCOLS / COLS_PER_BLOCK)  // 16

__global__ __launch_bounds__(256) void build_W(const float* __restrict__ weights,
                                               const int* __restrict__ src,
                                               const int* __restrict__ dst,
                                               float* __restrict__ W,
                                               int E, int S) {
    int e = blockIdx.x * blockDim.x + threadIdx.x;
    if (e >= E) return;
    int d = dst[e];
    if (d >= S) {
        // W is [256-S rows][S cols]
        atomicAdd(&W[(size_t)(d - S) * S + src[e]], weights[e]);
    }
}

__global__ __launch_bounds__(256) void gather_gemm(const float* __restrict__ loss,
                                                   const float* __restrict__ prev,
                                                   const float* __restrict__ params,
                                                   const float* __restrict__ W,
                                                   float* __restrict__ out,
                                                   int S) {
    const int n     = blockIdx.x >> 4;      // output row 0..127 (grid = nOut*16)
    const int chunk = blockIdx.x & (CHUNKS - 1);
    const int col   = chunk * COLS_PER_BLOCK + threadIdx.x * 4;

    const float* Wrow = W + (size_t)n * S;
    float4 acc = make_float4(0.f, 0.f, 0.f, 0.f);

    #pragma unroll 4
    for (int k = 0; k < S; ++k) {
        float w = Wrow[k];                  // same addr across block -> L1 broadcast
        if (w != 0.0f) {                    // wave-uniform branch: ~16/128 taken
            const float* row = (k == 0) ? loss
                             : (k == 1) ? prev
                             : params + (size_t)(k - 2) * DCOLS;
            const float4 f = *reinterpret_cast<const float4*>(row + col);
            acc.x = fmaf(w, f.x, acc.x);
            acc.y = fmaf(w, f.y, acc.y);
            acc.z = fmaf(w, f.z, acc.z);
            acc.w = fmaf(w, f.w, acc.w);
        }
    }
    *reinterpret_cast<float4*>(out + (size_t)n * DCOLS + col) = acc;
}

extern "C" void kernel_launch(void* const* d_in, const int* in_sizes, int n_in,
                              void* d_out, int out_size, void* d_ws, size_t ws_size,
                              hipStream_t stream) {
    const float* loss    = (const float*)d_in[0];
    const float* prev    = (const float*)d_in[1];
    const float* params  = (const float*)d_in[2];
    const float* weights = (const float*)d_in[3];
    const int*   src     = (const int*)d_in[4];
    const int*   dst     = (const int*)d_in[5];
    float*       out     = (float*)d_out;

    const int E    = in_sizes[3];              // 4096
    const int P    = in_sizes[2] / DCOLS;      // 126
    const int S    = 2 + P;                    // 128
    const int nOut = out_size / DCOLS;         // 128

    float* W = (float*)d_ws;                   // (nOut*S) floats = 64 KB
    size_t Wbytes = (size_t)nOut * S * sizeof(float);

    hipMemsetAsync(W, 0, Wbytes, stream);
    build_W<<<(E + 255) / 256, 256, 0, stream>>>(weights, src, dst, W, E, S);
    gather_gemm<<<nOut * CHUNKS, 256, 0, stream>>>(loss, prev, params, W, out, S);
}

// Round 2
// 13.947 us; speedup vs baseline: 1.9252x; 1.9252x over previous
//
#include <hip/hip_runtime.h>

// out[n][d] = sum_k W[n][k] * F[k][d],  n in [0,128), d in [0,16384)
// F = [loss; prev_loss; params] (128 x 16384 fp32), W built from 4096 edges:
// W[dst-S][src] += weight for edges with dst >= S (S = 2 + P = 128).
//
// Single-kernel design: each block owns (output row n, 2048-col chunk).
// It rebuilds its own W-row from the edge list in LDS (edges are 48 KB,
// L2-resident broadcast), compacts nonzero k's (~16 of 128), then streams
// F[k][chunk] with float4 loads, fp32 FMA accumulate, one coalesced write.
// bid = n*8 + chunk  =>  bid % 8 == chunk: one column-slice per XCD (1 MB
// working set per XCD L2, disjoint across XCDs).

#define DCOLS 16384
#define VEC 8                        // floats per thread
#define CPB (256 * VEC)              // 2048 cols per block
#define CHUNKS (DCOLS / CPB)         // 8
#define MAXS 132                     // >= S (=128), padded

__global__ __launch_bounds__(256) void fused_gather_gemm(
    const float* __restrict__ loss,
    const float* __restrict__ prev,
    const float* __restrict__ params,
    const float* __restrict__ weights,
    const int*   __restrict__ src,
    const int*   __restrict__ dst,
    float*       __restrict__ out,
    int E, int S) {
    __shared__ float Wrow[MAXS];
    __shared__ int   klist[MAXS];
    __shared__ int   cnt;

    const int tid   = threadIdx.x;
    const int n     = blockIdx.x >> 3;        // output row 0..127
    const int chunk = blockIdx.x & (CHUNKS - 1);

    if (tid < S) Wrow[tid] = 0.0f;
    if (tid == 0) cnt = 0;
    __syncthreads();

    // ---- build this row's W from the edge list (vectorized int4/float4) ----
    const int target = n + S;
    const int E4 = E & ~3;
    for (int e = tid * 4; e < E4; e += 256 * 4) {
        const int4   s4 = *reinterpret_cast<const int4*>(src + e);
        const int4   d4 = *reinterpret_cast<const int4*>(dst + e);
        const float4 w4 = *reinterpret_cast<const float4*>(weights + e);
        if (d4.x == target) atomicAdd(&Wrow[s4.x], w4.x);
        if (d4.y == target) atomicAdd(&Wrow[s4.y], w4.y);
        if (d4.z == target) atomicAdd(&Wrow[s4.z], w4.z);
        if (d4.w == target) atomicAdd(&Wrow[s4.w], w4.w);
    }
    for (int e = E4 + tid; e < E; e += 256) {   // tail (E not /4)
        if (dst[e] == target) atomicAdd(&Wrow[src[e]], weights[e]);
    }
    __syncthreads();

    // ---- compact nonzero k's ----
    if (tid < S && Wrow[tid] != 0.0f) {
        int p = atomicAdd(&cnt, 1);
        klist[p] = tid;
    }
    __syncthreads();

    // ---- stream the chunk: acc over ~16 nonzero rows of F ----
    const int col  = chunk * CPB + tid * 4;     // first float4
    const int col2 = col + 1024;                // second float4 (256 thr * 4)

    float4 a0 = make_float4(0.f, 0.f, 0.f, 0.f);
    float4 a1 = make_float4(0.f, 0.f, 0.f, 0.f);

    const int m = cnt;
    #pragma unroll 4
    for (int i = 0; i < m; ++i) {
        const int   k = klist[i];
        const float w = Wrow[k];
        const float* row = (k == 0) ? loss
                         : (k == 1) ? prev
                         : params + (size_t)(k - 2) * DCOLS;
        const float4 f0 = *reinterpret_cast<const float4*>(row + col);
        const float4 f1 = *reinterpret_cast<const float4*>(row + col2);
        a0.x = fmaf(w, f0.x, a0.x);
        a0.y = fmaf(w, f0.y, a0.y);
        a0.z = fmaf(w, f0.z, a0.z);
        a0.w = fmaf(w, f0.w, a0.w);
        a1.x = fmaf(w, f1.x, a1.x);
        a1.y = fmaf(w, f1.y, a1.y);
        a1.z = fmaf(w, f1.z, a1.z);
        a1.w = fmaf(w, f1.w, a1.w);
    }

    float* o = out + (size_t)n * DCOLS;
    *reinterpret_cast<float4*>(o + col)  = a0;
    *reinterpret_cast<float4*>(o + col2) = a1;
}

extern "C" void kernel_launch(void* const* d_in, const int* in_sizes, int n_in,
                              void* d_out, int out_size, void* d_ws, size_t ws_size,
                              hipStream_t stream) {
    const float* loss    = (const float*)d_in[0];
    const float* prev    = (const float*)d_in[1];
    const float* params  = (const float*)d_in[2];
    const float* weights = (const float*)d_in[3];
    const int*   src     = (const int*)d_in[4];
    const int*   dst     = (const int*)d_in[5];
    float*       out     = (float*)d_out;

    const int E    = in_sizes[3];              // 4096
    const int P    = in_sizes[2] / DCOLS;      // 126
    const int S    = 2 + P;                    // 128
    const int nOut = out_size / DCOLS;         // 128

    fused_gather_gemm<<<nOut * CHUNKS, 256, 0, stream>>>(
        loss, prev, params, weights, src, dst, out, E, S);
}